// Round 6
// baseline (347.066 us; speedup 1.0000x reference)
//
#include <hip/hip_runtime.h>
#include <hip/hip_cooperative_groups.h>
#include <hip/hip_bf16.h>
#include <cstdint>
#include <cstddef>

namespace cg = cooperative_groups;

// Sizes fixed by the reference problem.
#define DMODEL 1024
#define BATCH  4
#define SEQ    4096
#define BSROWS (BATCH*SEQ)     // 16384
#define CHUNK  32
#define NCHUNK (SEQ/CHUNK)     // 128
#define NCH_T  (BATCH*NCHUNK)  // 512 total chunks

typedef __attribute__((ext_vector_type(8))) short bf16x8;
typedef __attribute__((ext_vector_type(4))) float f32x4;

// ---- helpers ---------------------------------------------------------------

__device__ __forceinline__ unsigned short f2bf(float f) {
  union { float f; uint32_t u; } v; v.f = f;
  uint32_t u = v.u;
  u += 0x7FFFu + ((u >> 16) & 1u);   // round-to-nearest-even
  return (unsigned short)(u >> 16);
}

__device__ __forceinline__ float sigmoid_dev(const float* dp) {
  return 1.0f / (1.0f + expf(-dp[0]));
}

typedef __attribute__((address_space(1))) void void_g;
typedef __attribute__((address_space(3))) void void_l;

__device__ __forceinline__ void gl2lds16(const void* g, void* l) {
  __builtin_amdgcn_global_load_lds((void_g*)g, (void_l*)l, 16, 0, 0);
}

// ---- 64x64-tile NT K-loop (BK=64, XOR-8 swizzle) ---------------------------
__device__ __forceinline__ void kloop64(
    const unsigned short* __restrict__ A, const unsigned short* __restrict__ B,
    int m0, int n0, f32x4 acc[2][2],
    unsigned short* As, unsigned short* Bs, int tid) {
  int lane = tid & 63, w = tid >> 6, wm = w & 1, wn = w >> 1;
  int quad = lane >> 4, l16 = lane & 15;
  int r = tid >> 3, cch = tid & 7;
  int g = cch ^ (r & 7);
  const bf16x8* Av = (const bf16x8*)As;
  const bf16x8* Bv = (const bf16x8*)Bs;
  for (int k0 = 0; k0 < DMODEL; k0 += 64) {
    gl2lds16(A + (size_t)(m0 + r) * DMODEL + k0 + g * 8,      As + r * 64 + cch * 8);
    gl2lds16(A + (size_t)(m0 + 32 + r) * DMODEL + k0 + g * 8, As + (32 + r) * 64 + cch * 8);
    gl2lds16(B + (size_t)(n0 + r) * DMODEL + k0 + g * 8,      Bs + r * 64 + cch * 8);
    gl2lds16(B + (size_t)(n0 + 32 + r) * DMODEL + k0 + g * 8, Bs + (32 + r) * 64 + cch * 8);
    __syncthreads();
    #pragma unroll
    for (int kk = 0; kk < 2; ++kk) {
      bf16x8 af[2], bfr[2];
      #pragma unroll
      for (int i = 0; i < 2; ++i) {
        int rowA = wm * 32 + i * 16 + l16;
        af[i]  = Av[rowA * 8 + ((kk * 4 + quad) ^ (l16 & 7))];
        int rowB = wn * 32 + i * 16 + l16;
        bfr[i] = Bv[rowB * 8 + ((kk * 4 + quad) ^ (l16 & 7))];
      }
      #pragma unroll
      for (int i = 0; i < 2; ++i)
        #pragma unroll
        for (int j = 0; j < 2; ++j)
          acc[i][j] = __builtin_amdgcn_mfma_f32_16x16x32_bf16(af[i], bfr[j], acc[i][j], 0, 0, 0);
    }
    __syncthreads();
  }
}

// ---- single cooperative kernel: prep + {Wc GEMM, chunk scan} + pout --------
// Grid 512 x 256 (2 blocks/CU co-resident; LDS 16KB, VGPR well under 256).
// Phase 1 (persistent loop over 2624 items):
//   items [0,512)    : local scan per (b,chunk) -> hv(bf16), carry(f32)
//   items [512,1536) : W_f row -> bf16 + bb[e]=dot(W_f[e],b_up)
//   items [1536,2560): W_up 32x32 tile -> bf16 transposed
//   items [2560,2624): lbeta/cbeta mask-only scans (one thread per row)
// grid.sync()
// Phase 2: blocks [0,256): Wc 64x64 tiles; blocks [256,272): chunk-level scan
// grid.sync()
// Phase 3: blocks [0,128): Pout = Pbf@Wc^T + pbeta*bb
__global__ __launch_bounds__(256) void fused_pre(
    const float* __restrict__ x, const float* __restrict__ mask,
    const float* __restrict__ W_up, const float* __restrict__ b_up,
    const float* __restrict__ W_f, const float* __restrict__ dp,
    unsigned short* __restrict__ Wf_bf, unsigned short* __restrict__ WupT,
    float* __restrict__ bb, unsigned short* __restrict__ hv,
    float* __restrict__ carry, float* __restrict__ lbeta,
    float* __restrict__ cbeta, unsigned short* __restrict__ Wc,
    unsigned short* __restrict__ Pbf, float* __restrict__ pbeta,
    float* __restrict__ Pout) {
  cg::grid_group grid = cg::this_grid();
  __shared__ unsigned short As[64 * 64];   // 8 KB (also reused as f32 tile)
  __shared__ unsigned short Bs[64 * 64];   // 8 KB (also reused as reduce buf)
  int blk = blockIdx.x;
  int tid = threadIdx.x;

  // ---------------- Phase 1 ----------------
  for (int item = blk; item < 2624; item += 512) {
    if (item < 512) {
      float decay = sigmoid_dev(dp);
      int b = item / NCHUNK, c = item % NCHUNK;
      int base = b * SEQ + c * CHUNK;
      const float4* xp = (const float4*)(x + (size_t)base * DMODEL);
      const float* mp = mask + base;
      float4 h = make_float4(0.f, 0.f, 0.f, 0.f);
      #pragma unroll 8
      for (int s = 0; s < CHUNK; ++s) {
        float m = mp[s];
        float4 xv = xp[(size_t)s * (DMODEL / 4) + tid];
        h.x = decay * h.x + m * xv.x;
        h.y = decay * h.y + m * xv.y;
        h.z = decay * h.z + m * xv.z;
        h.w = decay * h.w + m * xv.w;
        ushort4 o;
        o.x = f2bf(h.x); o.y = f2bf(h.y); o.z = f2bf(h.z); o.w = f2bf(h.w);
        ((ushort4*)hv)[(size_t)(base + s) * (DMODEL / 4) + tid] = o;
      }
      ((float4*)carry)[(size_t)item * (DMODEL / 4) + tid] = h;
    } else if (item < 1536) {
      // one W_f row: cast to bf16 + block-reduce dot with b_up
      int e = item - 512;
      int lane = tid & 63, w = tid >> 6;
      float* red = (float*)Bs;
      float4 v = ((const float4*)(W_f + (size_t)e * DMODEL))[tid];
      float4 bu = ((const float4*)b_up)[tid];
      ushort4 o;
      o.x = f2bf(v.x); o.y = f2bf(v.y); o.z = f2bf(v.z); o.w = f2bf(v.w);
      ((ushort4*)(Wf_bf + (size_t)e * DMODEL))[tid] = o;
      float s = v.x * bu.x + v.y * bu.y + v.z * bu.z + v.w * bu.w;
      #pragma unroll
      for (int off = 32; off; off >>= 1) s += __shfl_down(s, off);
      if (lane == 0) red[w] = s;
      __syncthreads();
      if (tid == 0) bb[e] = red[0] + red[1] + red[2] + red[3];
      __syncthreads();
    } else if (item < 2560) {
      // W_up 32x32 tile transpose + cast
      float (*tile)[33] = (float(*)[33])As;
      int id = item - 1536;
      int bx = id & 31, by = id >> 5;
      int tx = tid & 31, ty = tid >> 5;   // 32 x 8
      int xx = bx * 32 + tx;
      int y0 = by * 32;
      for (int j = ty; j < 32; j += 8)
        tile[j][tx] = W_up[(size_t)(y0 + j) * DMODEL + xx];
      __syncthreads();
      int ox = by * 32 + tx;
      int oy0 = bx * 32;
      for (int j = ty; j < 32; j += 8)
        WupT[(size_t)(oy0 + j) * DMODEL + ox] = f2bf(tile[tx][j]);
      __syncthreads();
    } else {
      // beta local scans: one thread per row
      float decay = sigmoid_dev(dp);
      int t = (item - 2560) * 256 + tid;    // 0..16383 global row
      int s = t & 31;
      int cbase = t & ~31;
      float hb = 0.f;
      for (int i = 0; i <= s; ++i)
        hb = decay * hb + mask[cbase + i];
      lbeta[t] = hb;
      if (s == 31) cbeta[t >> 5] = hb;
    }
  }

  grid.sync();

  // ---------------- Phase 2 ----------------
  if (blk < 256) {
    // Wc[e][d] = sum_c Wf[e][c] * WupT[d][c]
    int mt = blk >> 4, nt = blk & 15;
    f32x4 acc[2][2] = {};
    kloop64(Wf_bf, WupT, mt * 64, nt * 64, acc, As, Bs, tid);
    int lane = tid & 63, w = tid >> 6, wm = w & 1, wn = w >> 1;
    int quad = lane >> 4, l16 = lane & 15;
    #pragma unroll
    for (int j = 0; j < 2; ++j) {
      int col = nt * 64 + wn * 32 + j * 16 + l16;
      #pragma unroll
      for (int i = 0; i < 2; ++i) {
        int rowb = mt * 64 + wm * 32 + i * 16 + quad * 4;
        #pragma unroll
        for (int rr = 0; rr < 4; ++rr)
          Wc[(size_t)(rowb + rr) * DMODEL + col] = f2bf(acc[i][j][rr]);
      }
    }
  } else if (blk < 272) {
    // exclusive chunk scan: Pbf[c] = state entering chunk c (bf16), pbeta f32
    float decay = sigmoid_dev(dp);
    float dL = powf(decay, (float)CHUNK);
    int gid = (blk - 256) * 256 + tid;   // 0 .. 4095
    int b = gid >> 10, dd = gid & 1023;
    float P = 0.f;
    for (int c0 = 0; c0 < NCHUNK; c0 += 8) {
      float v[8];
      #pragma unroll
      for (int j = 0; j < 8; ++j)
        v[j] = carry[(size_t)(b * NCHUNK + c0 + j) * DMODEL + dd];
      #pragma unroll
      for (int j = 0; j < 8; ++j) {
        Pbf[(size_t)(b * NCHUNK + c0 + j) * DMODEL + dd] = f2bf(P);
        P = dL * P + v[j];
      }
    }
    if (dd == 0) {
      float Pb = 0.f;
      for (int c0 = 0; c0 < NCHUNK; c0 += 16) {
        float v[16];
        #pragma unroll
        for (int j = 0; j < 16; ++j) v[j] = cbeta[b * NCHUNK + c0 + j];
        #pragma unroll
        for (int j = 0; j < 16; ++j) {
          pbeta[b * NCHUNK + c0 + j] = Pb;
          Pb = dL * Pb + v[j];
        }
      }
    }
  }

  grid.sync();

  // ---------------- Phase 3 ----------------
  if (blk < 128) {
    int mt = blk >> 4, nt = blk & 15;  // 8 x 16
    f32x4 acc[2][2] = {};
    kloop64(Pbf, Wc, mt * 64, nt * 64, acc, As, Bs, tid);
    int lane = tid & 63, w = tid >> 6, wm = w & 1, wn = w >> 1;
    int quad = lane >> 4, l16 = lane & 15;
    #pragma unroll
    for (int j = 0; j < 2; ++j) {
      int col = nt * 64 + wn * 32 + j * 16 + l16;
      float bbv = bb[col];
      #pragma unroll
      for (int i = 0; i < 2; ++i) {
        int rowb = mt * 64 + wm * 32 + i * 16 + quad * 4;
        #pragma unroll
        for (int rr = 0; rr < 4; ++rr) {
          int row = rowb + rr;
          Pout[(size_t)row * DMODEL + col] = acc[i][j][rr] + pbeta[row] * bbv;
        }
      }
    }
  }
}

// ---- main GEMM: out = hv@Wc^T + decay^(s+1)*Pout[chunk] + lbeta*bb + b_f ---
// 128x128 tile, BK=32 (16 KB LDS), phi-swizzled conflict-free ds_read_b128,
// m-major block mapping (same-m blocks share an XCD). r5 operating point:
// VGPR ~116, no min-waves bound (r4 showed pinning VGPR=64 regresses).
__global__ __launch_bounds__(256) void gemm_main(
    const unsigned short* __restrict__ A,    // hv (local scans) bf16 [16384][1024]
    const unsigned short* __restrict__ Bm,   // Wc bf16 [1024][1024] rows=e
    const float* __restrict__ Pout,          // [512][1024]
    const float* __restrict__ lbeta,
    const float* __restrict__ bb,
    const float* __restrict__ bias_f,
    const float* __restrict__ dp,
    float* __restrict__ out) {
  __shared__ unsigned short As[128 * 32];   // 8 KB
  __shared__ unsigned short Bs[128 * 32];   // 8 KB
  __shared__ float dpow[CHUNK];
  int tid = threadIdx.x;
  if (tid < CHUNK) {
    float decay = sigmoid_dev(dp);
    dpow[tid] = powf(decay, (float)(tid + 1));
  }
  int lane = tid & 63, w = tid >> 6, wm = w & 1, wn = w >> 1;
  int quad = lane >> 4, l16 = lane & 15;
  int r = tid >> 2;                 // 0..63
  int c4 = tid & 3;                 // phys chunk slot
  int g = c4 ^ ((r >> 1) & 3);      // global chunk to fetch
  int phi = (l16 >> 1) & 3;         // reader-side swizzle
  int m0 = (blockIdx.x & 127) * 128;
  int n0 = (blockIdx.x >> 7) * 128;
  f32x4 acc[4][4] = {};
  const bf16x8* Av = (const bf16x8*)As;
  const bf16x8* Bv = (const bf16x8*)Bs;
  for (int k0 = 0; k0 < DMODEL; k0 += 32) {
    gl2lds16(A + (size_t)(m0 + r) * DMODEL + k0 + g * 8,        As + r * 32 + c4 * 8);
    gl2lds16(A + (size_t)(m0 + 64 + r) * DMODEL + k0 + g * 8,   As + (64 + r) * 32 + c4 * 8);
    gl2lds16(Bm + (size_t)(n0 + r) * DMODEL + k0 + g * 8,       Bs + r * 32 + c4 * 8);
    gl2lds16(Bm + (size_t)(n0 + 64 + r) * DMODEL + k0 + g * 8,  Bs + (64 + r) * 32 + c4 * 8);
    __syncthreads();
    bf16x8 af[4], bfr[4];
    #pragma unroll
    for (int i = 0; i < 4; ++i) {
      int rowA = wm * 64 + i * 16 + l16;
      af[i]  = Av[rowA * 4 + (quad ^ phi)];
      int rowB = wn * 64 + i * 16 + l16;
      bfr[i] = Bv[rowB * 4 + (quad ^ phi)];
    }
    #pragma unroll
    for (int i = 0; i < 4; ++i)
      #pragma unroll
      for (int j = 0; j < 4; ++j)
        acc[i][j] = __builtin_amdgcn_mfma_f32_16x16x32_bf16(af[i], bfr[j], acc[i][j], 0, 0, 0);
    __syncthreads();
  }
  #pragma unroll
  for (int j = 0; j < 4; ++j) {
    int col = n0 + wn * 64 + j * 16 + l16;
    float bbv = bb[col];
    float bfv = bias_f[col];
    #pragma unroll
    for (int i = 0; i < 4; ++i) {
      int rowb = m0 + wm * 64 + i * 16 + quad * 4;
      #pragma unroll
      for (int rr = 0; rr < 4; ++rr) {
        int row = rowb + rr;
        float po = Pout[(size_t)(row >> 5) * DMODEL + col];
        out[(size_t)row * DMODEL + col] =
            acc[i][j][rr] + dpow[row & 31] * po + lbeta[row] * bbv + bfv;
      }
    }
  }
}

// ---- launch ----------------------------------------------------------------

extern "C" void kernel_launch(void* const* d_in, const int* in_sizes, int n_in,
                              void* d_out, int out_size, void* d_ws, size_t ws_size,
                              hipStream_t stream) {
  const float* x    = (const float*)d_in[0];
  const float* mask = (const float*)d_in[1];
  const float* W_up = (const float*)d_in[2];
  const float* b_up = (const float*)d_in[3];
  const float* W_f  = (const float*)d_in[4];
  const float* b_f  = (const float*)d_in[5];
  const float* dp   = (const float*)d_in[6];
  float* out = (float*)d_out;

  char* ws = (char*)d_ws;
  unsigned short* hv    = (unsigned short*)(ws);                 // 32 MB
  unsigned short* Wc    = (unsigned short*)(ws + 33554432);      // 2 MB
  unsigned short* Wf_bf = (unsigned short*)(ws + 35651584);      // 2 MB
  unsigned short* WupT  = (unsigned short*)(ws + 37748736);      // 2 MB
  float* carry  = (float*)(ws + 39845888);                       // 2 MB
  unsigned short* Pbf = (unsigned short*)(ws + 41943040);        // 1 MB
  float* Pout   = (float*)(ws + 42991616);                       // 2 MB
  float* lbeta  = (float*)(ws + 45088768);                       // 64 KB
  float* cbeta  = (float*)(ws + 45154304);                       // 2 KB
  float* pbeta  = (float*)(ws + 45156352);                       // 2 KB
  float* bb     = (float*)(ws + 45158400);                       // 4 KB

  void* cargs[] = {
    (void*)&x, (void*)&mask, (void*)&W_up, (void*)&b_up, (void*)&W_f,
    (void*)&dp, (void*)&Wf_bf, (void*)&WupT, (void*)&bb, (void*)&hv,
    (void*)&carry, (void*)&lbeta, (void*)&cbeta, (void*)&Wc, (void*)&Pbf,
    (void*)&pbeta, (void*)&Pout
  };
  hipLaunchCooperativeKernel((void*)fused_pre, dim3(512), dim3(256),
                             cargs, 0, stream);
  gemm_main<<<1024, 256, 0, stream>>>(hv, Wc, Pout, lbeta, bb, b_f, dp, out);
}